// Round 1
// baseline (99.388 us; speedup 1.0000x reference)
//
#include <hip/hip_runtime.h>
#include <hip/hip_bf16.h>

// EmbeddingLoss: loss = sum_{i<j} [ same ? mse : max(0, 1-mse) ] / (B*(B-1))
// mse_ij = (sq_i + sq_j - 2*gram_ij)/D,  gram = E E^T.
// Plan: prep (fp32->bf16 + fp32 row norms) -> fused bf16-MFMA gram-tile kernel
// with hinge/select epilogue and atomicAdd reduction. Upper-triangle tiles only.

#define BN 8192
#define DK 256
#define NT 64            // BN / 128 tiles per dim
#define BK 64            // K-step

typedef __bf16 bf16x8 __attribute__((ext_vector_type(8)));
typedef float f32x4 __attribute__((ext_vector_type(4)));

typedef const __attribute__((address_space(1))) void* gas_vp;
typedef __attribute__((address_space(3))) void* las_vp;

static __device__ __forceinline__ unsigned short f2bf(float f) {
    unsigned u = __builtin_bit_cast(unsigned, f);
    u += 0x7fffu + ((u >> 16) & 1u);          // round-to-nearest-even
    return (unsigned short)(u >> 16);
}

// ---------------- prep: convert E to bf16 (ws) + fp32 row norms (ws) -------
__global__ __launch_bounds__(256) void embl_prep(
    const float* __restrict__ E, unsigned short* __restrict__ Eb,
    float* __restrict__ sq)
{
    const int lane = threadIdx.x & 63;
    const int wid  = threadIdx.x >> 6;
    const int row  = blockIdx.x * 4 + wid;    // one row per wave
    const float4 v = *(const float4*)(E + row * DK + lane * 4);
    float s = v.x*v.x + v.y*v.y + v.z*v.z + v.w*v.w;
    ushort4 o;
    o.x = f2bf(v.x); o.y = f2bf(v.y); o.z = f2bf(v.z); o.w = f2bf(v.w);
    *(ushort4*)(Eb + row * DK + lane * 4) = o;
    #pragma unroll
    for (int off = 32; off > 0; off >>= 1) s += __shfl_xor(s, off, 64);
    if (lane == 0) sq[row] = s;
}

// ---------------- main: fused gram tile + hinge epilogue -------------------
// 128x128 tile per block, 4 waves (2x2), each wave 64x64 via 4x4 frags of
// 16x16x32 bf16 MFMA. LDS staged via global_load_lds width=16 with XOR
// chunk-swizzle (linear dest + inverse-swizzled source + swizzled read).
__global__ __launch_bounds__(256) void embl_gram(
    const unsigned short* __restrict__ Ebu, const float* __restrict__ sq,
    const int* __restrict__ lab, float* __restrict__ out)
{
    __shared__ alignas(16) __bf16 As[128 * BK];
    __shared__ alignas(16) __bf16 Bs[128 * BK];
    __shared__ float wpart[4];

    // upper-triangle tile decode: bid -> (ti, tj), ti <= tj
    int t = blockIdx.x, ti = 0, rl = NT;
    while (t >= rl) { t -= rl; --rl; ++ti; }
    const int tj = ti + t;

    const int tid  = threadIdx.x;
    const int lane = tid & 63;
    const int wid  = tid >> 6;
    const int wr   = wid >> 1;      // wave row (0..1)
    const int wc   = wid & 1;       // wave col (0..1)

    f32x4 acc[4][4] = {};

    const char* Ebc = (const char*)Ebu;
    const long arow = (long)ti * 128;
    const long brow = (long)tj * 128;

    for (int kt = 0; kt < DK / BK; ++kt) {
        // stage A and B tiles: 128 rows x 8 chunks(16B) = 1024 chunks each,
        // 4 chunks per thread per tile. Linear LDS dest; source chunk index
        // inverse-XOR-swizzled (involution) so swizzled reads see true data.
        #pragma unroll
        for (int it = 0; it < 4; ++it) {
            const int c   = it * 256 + wid * 64 + lane;   // 0..1023
            const int row = c >> 3;
            const int sch = (c & 7) ^ (row & 7);
            const char* srcA = Ebc + (arow + row) * (DK * 2) + kt * (BK * 2) + sch * 16;
            const char* srcB = Ebc + (brow + row) * (DK * 2) + kt * (BK * 2) + sch * 16;
            __builtin_amdgcn_global_load_lds((gas_vp)srcA, (las_vp)((char*)As + c * 16), 16, 0, 0);
            __builtin_amdgcn_global_load_lds((gas_vp)srcB, (las_vp)((char*)Bs + c * 16), 16, 0, 0);
        }
        __syncthreads();

        #pragma unroll
        for (int ks = 0; ks < BK / 32; ++ks) {
            bf16x8 a[4], b[4];
            #pragma unroll
            for (int m = 0; m < 4; ++m) {
                const int r  = wr * 64 + m * 16 + (lane & 15);
                const int ch = ((lane >> 4) + ks * 4) ^ (r & 7);
                a[m] = *(const bf16x8*)((const char*)As + r * (BK * 2) + ch * 16);
            }
            #pragma unroll
            for (int n = 0; n < 4; ++n) {
                const int r  = wc * 64 + n * 16 + (lane & 15);
                const int ch = ((lane >> 4) + ks * 4) ^ (r & 7);
                b[n] = *(const bf16x8*)((const char*)Bs + r * (BK * 2) + ch * 16);
            }
            #pragma unroll
            for (int m = 0; m < 4; ++m)
                #pragma unroll
                for (int n = 0; n < 4; ++n)
                    acc[m][n] = __builtin_amdgcn_mfma_f32_16x16x32_bf16(
                        a[m], b[n], acc[m][n], 0, 0, 0);
        }
        __syncthreads();
    }

    // epilogue: C/D layout col=lane&15, row=(lane>>4)*4+reg  [m89-verified]
    const int gi0 = ti * 128 + wr * 64;
    const int gj0 = tj * 128 + wc * 64;
    const bool diag = (ti == tj);
    float lsum = 0.0f;

    #pragma unroll
    for (int m = 0; m < 4; ++m) {
        const int ibase = gi0 + m * 16 + (lane >> 4) * 4;
        float sqi[4]; int li[4];
        #pragma unroll
        for (int r = 0; r < 4; ++r) { sqi[r] = sq[ibase + r]; li[r] = lab[ibase + r]; }
        #pragma unroll
        for (int n = 0; n < 4; ++n) {
            const int j = gj0 + n * 16 + (lane & 15);
            const float sqj = sq[j];
            const int   lj  = lab[j];
            #pragma unroll
            for (int r = 0; r < 4; ++r) {
                const int i = ibase + r;
                const float mse = (sqi[r] + sqj - 2.0f * acc[m][n][r]) * (1.0f / 256.0f);
                float v = (li[r] == lj) ? mse : fmaxf(0.0f, 1.0f - mse);
                if (diag && i >= j) v = 0.0f;      // strict upper triangle
                lsum += v;
            }
        }
    }

    #pragma unroll
    for (int off = 32; off > 0; off >>= 1) lsum += __shfl_xor(lsum, off, 64);
    if (lane == 0) wpart[wid] = lsum;
    __syncthreads();
    if (tid == 0) {
        const float scale = 1.0f / ((float)BN * (float)(BN - 1)); // 1/67100672
        atomicAdd(out, (wpart[0] + wpart[1] + wpart[2] + wpart[3]) * scale);
    }
}

extern "C" void kernel_launch(void* const* d_in, const int* in_sizes, int n_in,
                              void* d_out, int out_size, void* d_ws, size_t ws_size,
                              hipStream_t stream) {
    const float* E   = (const float*)d_in[0];
    const int*   lab = (const int*)d_in[1];
    float*       out = (float*)d_out;

    unsigned short* Eb = (unsigned short*)d_ws;                       // 4 MiB
    float*          sq = (float*)((char*)d_ws + (size_t)BN * DK * 2); // 32 KiB

    hipMemsetAsync(d_out, 0, sizeof(float), stream);
    embl_prep<<<BN / 4, 256, 0, stream>>>(E, Eb, sq);
    embl_gram<<<NT * (NT + 1) / 2, 256, 0, stream>>>(Eb, sq, lab, out);
}